// Round 8
// baseline (336.194 us; speedup 1.0000x reference)
//
#include <hip/hip_runtime.h>
#include <hip/hip_cooperative_groups.h>
#include <stdint.h>

namespace cg = cooperative_groups;

constexpr int NN  = 50000;
constexpr int NE  = 800000;
constexpr int H   = 128;
constexpr int CAP = 48;    // bucket capacity; P(indeg>=48 | Poisson(16)) ~ e^-70
constexpr int RB  = 8;     // leaders per report iteration per block
constexpr int NBLK = 512;  // 2 blocks/CU guaranteed resident (launch_bounds(256,2))
constexpr int NTHR = 256;
constexpr int TOT  = NBLK * NTHR;  // 131072 persistent threads

typedef int vint4 __attribute__((ext_vector_type(4)));

__device__ __forceinline__ uint32_t f32key(float f) {
  uint32_t b = __float_as_uint(f);
  return (b & 0x80000000u) ? ~b : (b | 0x80000000u);
}

__global__ void __launch_bounds__(NTHR, 2) k_all(
    const float* __restrict__ x, const int* __restrict__ esrc, const int* __restrict__ edst,
    const float* __restrict__ Wle, const float* __restrict__ ble,
    const float* __restrict__ W1, const float* __restrict__ b1,
    const float* __restrict__ W2, const float* __restrict__ b2,
    unsigned long long* __restrict__ lkey, float* __restrict__ logits,
    int* __restrict__ cnt, int* __restrict__ slist, int* __restrict__ nsl,
    int* __restrict__ bucket, float* __restrict__ out) {
  cg::grid_group grid = cg::this_grid();
  const int tid = blockIdx.x * NTHR + threadIdx.x;
  const int* __restrict__ leader_lo = (const int*)lkey;  // leader[i] = leader_lo[2*i]

  __shared__ float sm[RB][H];
  __shared__ float hm[RB][H];
  __shared__ int   ss[RB][CAP];
  __shared__ int   nodes[RB];
  __shared__ int   craw[RB];
  __shared__ int   ns_sh;

  // ---- P0: logits, self-key init, cnt/nsl zero (all cross-block stores NT) ----
  if (tid == 0) __builtin_nontemporal_store(0, nsl);
  {
    int gw = tid >> 6, lane = tid & 63;
    for (int row = gw; row < NN; row += (TOT >> 6)) {
      const float* xr = x + (size_t)row * H;
      float v = xr[lane] * Wle[lane] + xr[lane + 64] * Wle[lane + 64];
      for (int off = 32; off > 0; off >>= 1) v += __shfl_xor(v, off, 64);
      if (lane == 0) {
        float lg = v + ble[0];
        __builtin_nontemporal_store(lg, &logits[row]);
        unsigned long long sk =
            ((unsigned long long)f32key(lg) << 32) | (unsigned long long)(uint32_t)row;
        __builtin_nontemporal_store(sk, &lkey[row]);
        __builtin_nontemporal_store(0, &cnt[row]);
      }
    }
  }
  grid.sync();

  // ---- P1: election; 4-edge batches, fire-and-forget atomicMax ----
  for (int g = tid; g < NE / 4; g += TOT) {
    vint4 s4 = __builtin_nontemporal_load((const vint4*)esrc + g);
    vint4 d4 = __builtin_nontemporal_load((const vint4*)edst + g);
    float lg[4];
#pragma unroll
    for (int i = 0; i < 4; ++i) lg[i] = logits[s4[i]];
#pragma unroll
    for (int i = 0; i < 4; ++i) {
      unsigned long long key =
          ((unsigned long long)f32key(lg[i]) << 32) | (unsigned long long)(uint32_t)s4[i];
      atomicMax(&lkey[d4[i]], key);
    }
  }
  grid.sync();

  // ---- P2: self-leader list + bucket placement ----
  for (int t = tid; t < NN; t += TOT) {
    if (leader_lo[2 * t] == t) {
      int p = atomicAdd(nsl, 1);
      __builtin_nontemporal_store(t, &slist[p]);
    }
  }
  for (int g = tid; g < NE / 4; g += TOT) {
    vint4 d4 = __builtin_nontemporal_load((const vint4*)edst + g);
    int L[4];
#pragma unroll
    for (int i = 0; i < 4; ++i) L[i] = leader_lo[2 * d4[i]];
#pragma unroll
    for (int i = 0; i < 4; ++i) {
      if (L[i] == d4[i]) {  // dst is self-leader: its report is read
        int s = esrc[g * 4 + i];  // lazy: ~6% reach here
        int slot = atomicAdd(&cnt[d4[i]], 1);
        if (slot < CAP) __builtin_nontemporal_store(s, &bucket[(size_t)d4[i] * CAP + slot]);
      }
    }
  }
  grid.sync();

  // ---- P3: fused neighbor-mean + MLP for self-leaders ----
  if (threadIdx.x == 0) ns_sh = atomicAdd(nsl, 0);  // memory-side read (L2-stale-proof)
  __syncthreads();
  const int ns = ns_sh;
  {
    int j = threadIdx.x & 127, half = threadIdx.x >> 7;
    for (int base = blockIdx.x * RB; base < ns; base += NBLK * RB) {
      int v = min(RB, ns - base);
      if (threadIdx.x < RB) {
        int node = slist[base + min((int)threadIdx.x, v - 1)];
        nodes[threadIdx.x] = node;
        craw[threadIdx.x] = cnt[node];
      }
      __syncthreads();
      for (int r = half; r < v; r += 2) {
        int cc = min(craw[r], CAP);
        if (j < cc) ss[r][j] = bucket[(size_t)nodes[r] * CAP + j];
      }
      __syncthreads();
      for (int rp = 0; rp < RB / 2; ++rp) {
        int r = 2 * rp + half;
        if (r >= v) break;
        int c = craw[r], cc = min(c, CAP);
        double a0 = 0.0, a1 = 0.0;
        int e = 0;
        for (; e + 1 < cc; e += 2) {
          a0 += (double)x[(size_t)ss[r][e] * H + j];
          a1 += (double)x[(size_t)ss[r][e + 1] * H + j];
        }
        if (e < cc) a0 += (double)x[(size_t)ss[r][e] * H + j];
        sm[r][j] = (float)(a0 + a1) * (1.0f / (float)max(c, 1));
      }
      __syncthreads();

      float acc[RB / 2];
#pragma unroll
      for (int rr = 0; rr < RB / 2; ++rr) acc[rr] = b1[j];
      for (int k = 0; k < H; ++k) {
        float w = W1[k * H + j];
#pragma unroll
        for (int rr = 0; rr < RB / 2; ++rr)
          acc[rr] = fmaf(sm[half * (RB / 2) + rr][k], w, acc[rr]);
      }
#pragma unroll
      for (int rr = 0; rr < RB / 2; ++rr)
        hm[half * (RB / 2) + rr][j] =
            0.5f * acc[rr] * (1.0f + erff(acc[rr] * 0.70710678118654752f));
      __syncthreads();

#pragma unroll
      for (int rr = 0; rr < RB / 2; ++rr) acc[rr] = b2[j];
      for (int k = 0; k < H; ++k) {
        float w = W2[k * H + j];
#pragma unroll
        for (int rr = 0; rr < RB / 2; ++rr)
          acc[rr] = fmaf(hm[half * (RB / 2) + rr][k], w, acc[rr]);
      }
#pragma unroll
      for (int rr = 0; rr < RB / 2; ++rr) {
        int r = half * (RB / 2) + rr;
        if (r < v)
          __builtin_nontemporal_store(acc[rr], &out[(size_t)nodes[r] * H + j]);
      }
      __syncthreads();
    }
  }
  grid.sync();

  // ---- P4: non-self-leader rows copy their leader's report (or zero) ----
  for (int g = tid; g < NN * 32; g += TOT) {
    int i = g >> 5, q = g & 31;
    int L = leader_lo[2 * i];
    if (L == i) continue;
    float4 v = make_float4(0.f, 0.f, 0.f, 0.f);
    if (leader_lo[2 * L] == L)
      v = *(const float4*)(out + (size_t)L * H + q * 4);
    float* o = out + (size_t)i * H + q * 4;
    __builtin_nontemporal_store(v.x, o + 0);
    __builtin_nontemporal_store(v.y, o + 1);
    __builtin_nontemporal_store(v.z, o + 2);
    __builtin_nontemporal_store(v.w, o + 3);
  }
}

extern "C" void kernel_launch(void* const* d_in, const int* in_sizes, int n_in,
                              void* d_out, int out_size, void* d_ws, size_t ws_size,
                              hipStream_t stream) {
  (void)in_sizes; (void)n_in; (void)out_size; (void)ws_size;
  const float* x   = (const float*)d_in[0];
  const int* ei    = (const int*)d_in[1];   // [2][NE] int32
  const float* Wle = (const float*)d_in[2];
  const float* ble = (const float*)d_in[3];
  const float* W1  = (const float*)d_in[4];
  const float* b1  = (const float*)d_in[5];
  const float* W2  = (const float*)d_in[6];
  const float* b2  = (const float*)d_in[7];
  float* out       = (float*)d_out;

  char* ws = (char*)d_ws;
  unsigned long long* lkey = (unsigned long long*)ws;        // 400000 B
  float* logits = (float*)(ws + 400000);                     // 200000 B
  int*   cnt    = (int*)  (ws + 600000);                     // 200000 B
  int*   slist  = (int*)  (ws + 800000);                     // 200000 B
  int*   nsl    = (int*)  (ws + 1000000);                    // 256 B
  int*   bucket = (int*)  (ws + 1000256);                    // NN*CAP*4 = 9.6 MB

  const int* esrc = ei;
  const int* edst = ei + NE;

  void* args[] = {(void*)&x, (void*)&esrc, (void*)&edst, (void*)&Wle, (void*)&ble,
                  (void*)&W1, (void*)&b1, (void*)&W2, (void*)&b2,
                  (void*)&lkey, (void*)&logits, (void*)&cnt, (void*)&slist,
                  (void*)&nsl, (void*)&bucket, (void*)&out};
  hipLaunchCooperativeKernel((const void*)k_all, dim3(NBLK), dim3(NTHR), args, 0, stream);
}

// Round 9
// 101.905 us; speedup vs baseline: 3.2991x; 3.2991x over previous
//
#include <hip/hip_runtime.h>
#include <stdint.h>

constexpr int NN  = 50000;
constexpr int NE  = 800000;
constexpr int H   = 128;
constexpr int CAP = 48;   // bucket capacity; P(indeg>=48 | Poisson(16)) ~ e^-70
constexpr int RB  = 8;    // leaders per report block
constexpr int NX  = 8;    // XCDs (shadow copies)

__device__ __forceinline__ uint32_t f32key(float f) {
  uint32_t b = __float_as_uint(f);
  return (b & 0x80000000u) ? ~b : (b | 0x80000000u);
}

// K1: logits + shadow init (copy0 = self-key, copies 1..7 = 0) + cnt/nsl zero.
__global__ void k_logits(const float* __restrict__ x,
                         const float* __restrict__ Wle, const float* __restrict__ ble,
                         float* __restrict__ logits, unsigned long long* __restrict__ lkeyX,
                         int* __restrict__ cnt, int* __restrict__ nsl) {
  int gid  = blockIdx.x * blockDim.x + threadIdx.x;
  int wave = gid >> 6, lane = threadIdx.x & 63;
  if (gid == 0) *nsl = 0;
  if (wave >= NN) return;
  const float* xr = x + (size_t)wave * H;
  float v = xr[lane] * Wle[lane] + xr[lane + 64] * Wle[lane + 64];
  for (int off = 32; off > 0; off >>= 1) v += __shfl_xor(v, off, 64);
  if (lane >= 1 && lane < NX) lkeyX[(size_t)lane * NN + wave] = 0ull;
  if (lane == 0) {
    float lg = v + ble[0];
    logits[wave] = lg;
    lkeyX[wave] = ((unsigned long long)f32key(lg) << 32) | (unsigned long long)(uint32_t)wave;
    cnt[wave] = 0;
  }
}

// K2: election with XCD-LOCAL (workgroup-scope) atomics into the XCD's own shadow.
// Same-address RMWs always come from one XCD -> its L2 serializes them (atomicity OK);
// kernel-end writeback publishes the shadows for k_merge.
__global__ void k_elect(const int* __restrict__ esrc, const int* __restrict__ edst,
                        const float* __restrict__ logits,
                        unsigned long long* __restrict__ lkeyX) {
  uint32_t xcc;
  asm volatile("s_getreg_b32 %0, hwreg(HW_REG_XCC_ID)" : "=s"(xcc));
  unsigned long long* __restrict__ my = lkeyX + (size_t)(xcc & (NX - 1)) * NN;
  int e = blockIdx.x * blockDim.x + threadIdx.x;
  if (e >= NE) return;
  int s = __builtin_nontemporal_load(&esrc[e]);
  int d = __builtin_nontemporal_load(&edst[e]);
  unsigned long long key =
      ((unsigned long long)f32key(logits[s]) << 32) | (unsigned long long)(uint32_t)s;
  __hip_atomic_fetch_max(&my[d], key, __ATOMIC_RELAXED, __HIP_MEMORY_SCOPE_WORKGROUP);
}

// K2b: merge shadows -> final key array; build self-leader list.
__global__ void k_merge(const unsigned long long* __restrict__ lkeyX,
                        unsigned long long* __restrict__ lkeyF,
                        int* __restrict__ slist, int* __restrict__ nsl) {
  int t = blockIdx.x * blockDim.x + threadIdx.x;
  if (t >= NN) return;
  unsigned long long m = lkeyX[t];
#pragma unroll
  for (int c = 1; c < NX; ++c) {
    unsigned long long v = lkeyX[(size_t)c * NN + t];
    m = (v > m) ? v : m;
  }
  __builtin_nontemporal_store(m, &lkeyF[t]);
  if ((uint32_t)m == (uint32_t)t) {
    int p = atomicAdd(nsl, 1);
    slist[p] = t;
  }
}

// K3: bucket passing edges by destination (1 edge/thread, lazy esrc).
__global__ void k_place(const int* __restrict__ esrc, const int* __restrict__ edst,
                        const unsigned long long* __restrict__ lkeyF,
                        int* __restrict__ cnt, int* __restrict__ bucket) {
  const int* __restrict__ leader_lo = (const int*)lkeyF;  // leader[i] = leader_lo[2*i]
  int t = blockIdx.x * blockDim.x + threadIdx.x;
  if (t >= NE) return;
  int d = __builtin_nontemporal_load(&edst[t]);
  if (leader_lo[2 * d] != d) return;  // dst's report never read
  int s = esrc[t];                    // lazy: only ~6% of edges reach here
  int slot = atomicAdd(&cnt[d], 1);
  if (slot < CAP) bucket[(size_t)d * CAP + slot] = s;
}

// K4: fused neighbor-mean + 2-layer MLP; RB leaders per 256-thread block.
__global__ void __launch_bounds__(256) k_report(
    const int* __restrict__ slist, const int* __restrict__ nsl,
    const int* __restrict__ cnt, const int* __restrict__ bucket,
    const float* __restrict__ x,
    const float* __restrict__ W1, const float* __restrict__ b1,
    const float* __restrict__ W2, const float* __restrict__ b2,
    float* __restrict__ out) {
  int base = blockIdx.x * RB;
  int ns = *nsl;
  if (base >= ns) return;
  int v = min(RB, ns - base);

  __shared__ float sm[RB][H];
  __shared__ float hm[RB][H];
  __shared__ int   ss[RB][CAP];
  __shared__ int   nodes[RB];
  __shared__ int   craw[RB];

  int tid = threadIdx.x;
  int j = tid & 127, half = tid >> 7;

  if (tid < RB) {
    int node = slist[base + min(tid, v - 1)];
    nodes[tid] = node;
    craw[tid] = cnt[node];
  }
  __syncthreads();
  for (int r = half; r < v; r += 2) {
    int cc = min(craw[r], CAP);
    if (j < cc) ss[r][j] = bucket[(size_t)nodes[r] * CAP + j];
  }
  __syncthreads();
  // gather nmean (order-insensitive exact f64 accumulation)
  for (int rp = 0; rp < RB / 2; ++rp) {
    int r = 2 * rp + half;
    if (r >= v) break;
    int c = craw[r], cc = min(c, CAP);
    double a0 = 0.0, a1 = 0.0;
    int e = 0;
    for (; e + 1 < cc; e += 2) {
      a0 += (double)x[(size_t)ss[r][e] * H + j];
      a1 += (double)x[(size_t)ss[r][e + 1] * H + j];
    }
    if (e < cc) a0 += (double)x[(size_t)ss[r][e] * H + j];
    sm[r][j] = (float)(a0 + a1) * (1.0f / (float)max(c, 1));
  }
  __syncthreads();

  float acc[RB / 2];
#pragma unroll
  for (int rr = 0; rr < RB / 2; ++rr) acc[rr] = b1[j];
  for (int k = 0; k < H; ++k) {
    float w = W1[k * H + j];
#pragma unroll
    for (int rr = 0; rr < RB / 2; ++rr)
      acc[rr] = fmaf(sm[half * (RB / 2) + rr][k], w, acc[rr]);
  }
#pragma unroll
  for (int rr = 0; rr < RB / 2; ++rr)
    hm[half * (RB / 2) + rr][j] =
        0.5f * acc[rr] * (1.0f + erff(acc[rr] * 0.70710678118654752f));
  __syncthreads();

#pragma unroll
  for (int rr = 0; rr < RB / 2; ++rr) acc[rr] = b2[j];
  for (int k = 0; k < H; ++k) {
    float w = W2[k * H + j];
#pragma unroll
    for (int rr = 0; rr < RB / 2; ++rr)
      acc[rr] = fmaf(hm[half * (RB / 2) + rr][k], w, acc[rr]);
  }
#pragma unroll
  for (int rr = 0; rr < RB / 2; ++rr) {
    int r = half * (RB / 2) + rr;
    if (r < v)
      __builtin_nontemporal_store(acc[rr], &out[(size_t)nodes[r] * H + j]);
  }
}

// K5: non-self-leader rows copy their leader's report (or zero).
__global__ void k_out(const unsigned long long* __restrict__ lkeyF,
                      float* __restrict__ out) {
  const int* __restrict__ leader_lo = (const int*)lkeyF;
  int g = blockIdx.x * blockDim.x + threadIdx.x;
  int i = g >> 5, q = g & 31;
  if (i >= NN) return;
  int L = leader_lo[2 * i];
  if (L == i) return;  // self-leader rows already final
  float4 v = make_float4(0.f, 0.f, 0.f, 0.f);
  if (leader_lo[2 * L] == L)
    v = *(const float4*)(out + (size_t)L * H + q * 4);
  float* o = out + (size_t)i * H + q * 4;
  __builtin_nontemporal_store(v.x, o + 0);
  __builtin_nontemporal_store(v.y, o + 1);
  __builtin_nontemporal_store(v.z, o + 2);
  __builtin_nontemporal_store(v.w, o + 3);
}

extern "C" void kernel_launch(void* const* d_in, const int* in_sizes, int n_in,
                              void* d_out, int out_size, void* d_ws, size_t ws_size,
                              hipStream_t stream) {
  (void)in_sizes; (void)n_in; (void)out_size; (void)ws_size;
  const float* x   = (const float*)d_in[0];
  const int* ei    = (const int*)d_in[1];   // [2][NE] int32
  const float* Wle = (const float*)d_in[2];
  const float* ble = (const float*)d_in[3];
  const float* W1  = (const float*)d_in[4];
  const float* b1  = (const float*)d_in[5];
  const float* W2  = (const float*)d_in[6];
  const float* b2  = (const float*)d_in[7];
  float* out       = (float*)d_out;

  char* ws = (char*)d_ws;
  unsigned long long* lkeyX = (unsigned long long*)ws;       // NX*NN*8 = 3.2 MB
  size_t off = (size_t)NX * NN * 8;
  unsigned long long* lkeyF = (unsigned long long*)(ws + off);       // 400000 B
  float* logits = (float*)(ws + off + 400000);               // 200000 B
  int*   cnt    = (int*)  (ws + off + 600000);               // 200000 B
  int*   slist  = (int*)  (ws + off + 800000);               // 200000 B
  int*   nsl    = (int*)  (ws + off + 1000000);              // 256 B
  int*   bucket = (int*)  (ws + off + 1000256);              // NN*CAP*4 = 9.6 MB

  const int* esrc = ei;
  const int* edst = ei + NE;

  k_logits<<<(NN * 64 + 255) / 256, 256, 0, stream>>>(x, Wle, ble, logits, lkeyX, cnt, nsl);
  k_elect<<<(NE + 255) / 256, 256, 0, stream>>>(esrc, edst, logits, lkeyX);
  k_merge<<<(NN + 255) / 256, 256, 0, stream>>>(lkeyX, lkeyF, slist, nsl);
  k_place<<<(NE + 255) / 256, 256, 0, stream>>>(esrc, edst, lkeyF, cnt, bucket);
  k_report<<<(NN + RB - 1) / RB, 256, 0, stream>>>(slist, nsl, cnt, bucket, x,
                                                   W1, b1, W2, b2, out);
  k_out<<<(NN * 32 + 255) / 256, 256, 0, stream>>>(lkeyF, out);
}